// Round 2
// baseline (312.999 us; speedup 1.0000x reference)
//
#include <hip/hip_runtime.h>

// PointNet fused kernel for MI355X (gfx950) — round 2.
//
// Algebra: segment-MLP + cb are per-row constants -> cancel in the per-row
// min/max rescale. Only s1[m,n] = feat·cW[0:6] + relu(MLP3(feat))·cW[6:262]
// matters, then per-row rescale to [-1,1].
//
// Round-2 changes vs round 1 (which was 1 block/CU, 22% occupancy):
//  - single in-place h buffer (64 KB) instead of hA+hB (128 KB); extra
//    barrier between L2-read and L2-epilogue-write makes it safe.
//  - hF shrunk 10 KB -> 2 KB: layer-1 K is padded 6->32, but k>=8 slots are
//    zero, so hi>=1 lanes use a zero register B-fragment instead of LDS.
//  - sPart overlaid on dead hF; feat·cW[0:6] held in a register (fdot).
//  => LDS 147 KB -> 70 KB => 2 blocks/CU (16 waves/CU).
//  - epilogue bf16 pack via v_cvt_pk_bf16_f32 (1 instr / 2 values).

typedef __attribute__((ext_vector_type(8))) short short8;   // 8 bf16
typedef __attribute__((ext_vector_type(4))) float f32x4;    // MFMA accum
typedef __attribute__((ext_vector_type(4))) unsigned int u32x4;

#define THREADS 512

__device__ __forceinline__ unsigned short f2bf(float f) {
  union { float f; unsigned int u; } x; x.f = f;
  unsigned int r = x.u + 0x7fffu + ((x.u >> 16) & 1u);   // RNE
  return (unsigned short)(r >> 16);
}

__device__ __forceinline__ unsigned int cvt_pk_bf16(float lo, float hi) {
  unsigned int r;
  asm("v_cvt_pk_bf16_f32 %0, %1, %2" : "=v"(r) : "v"(lo), "v"(hi));
  return r;
}

// ---------------------------------------------------------------------------
// k0: pack weights into MFMA A-fragment order:
//   idx(s,ct,hi,col,j) = (((s*16+ct)*4+hi)*16+col)*8 + j
//   k = s*32 + hi*8 + j (zero past Kreal), c = ct*16 + col
// Regions (ushort): W1 @0 (8192), W2 @8192 (65536), W3 @73728 (65536)
// ---------------------------------------------------------------------------
__global__ void pn_pack(const float* __restrict__ W1,
                        const float* __restrict__ W2,
                        const float* __restrict__ W3,
                        unsigned short* __restrict__ wp) {
  int e = blockIdx.x * 256 + threadIdx.x;           // 0 .. 139263
  const float* src; int Kreal, base, r;
  if (e < 8192)       { src = W1; Kreal = 6;   base = 0;     r = e; }
  else if (e < 73728) { src = W2; Kreal = 256; base = 8192;  r = e - 8192; }
  else                { src = W3; Kreal = 256; base = 73728; r = e - 73728; }
  int j   = r & 7;
  int col = (r >> 3) & 15;
  int hi  = (r >> 7) & 3;
  int ct  = (r >> 9) & 15;
  int s   = r >> 13;
  int k = s * 32 + hi * 8 + j;
  int c = ct * 16 + col;
  float v = (k < Kreal) ? src[k * 256 + c] : 0.0f;
  wp[base + r] = f2bf(v);
}

// ---------------------------------------------------------------------------
// k1 helpers
// ---------------------------------------------------------------------------
__device__ __forceinline__ void gemm256(const unsigned short* __restrict__ wpL,
                                        const unsigned short* hbuf,
                                        int cgrp, int pgrp, int l15, int hi,
                                        f32x4 (&acc)[4][4]) {
#pragma unroll
  for (int ks = 0; ks < 8; ++ks) {
    short8 afr[4], bfr[4];
#pragma unroll
    for (int cf = 0; cf < 4; ++cf) {               // A = W fragments (global)
      int ct = cgrp * 4 + cf;
      afr[cf] = *(const short8*)(wpL + (((((ks * 16 + ct) * 4) + hi) * 16 + l15) << 3));
    }
#pragma unroll
    for (int pf = 0; pf < 4; ++pf) {               // B = h fragments (LDS, swz)
      int p = pgrp * 64 + pf * 16 + l15;
      int byteoff = ((p * 256 + ks * 32 + hi * 8) * 2) ^ ((p & 7) << 4);
      bfr[pf] = *(const short8*)((const char*)hbuf + byteoff);
    }
#pragma unroll
    for (int cf = 0; cf < 4; ++cf)
#pragma unroll
      for (int pf = 0; pf < 4; ++pf)
        acc[cf][pf] = __builtin_amdgcn_mfma_f32_16x16x32_bf16(
            afr[cf], bfr[pf], acc[cf][pf], 0, 0, 0);
  }
}

// bias + relu -> bf16 (cvt_pk) -> swizzled h buffer, b64 writes
__device__ __forceinline__ void epi_h(f32x4 (&acc)[4][4], unsigned short* dst,
                                      const float* bv,
                                      int cgrp, int pgrp, int l15, int hi) {
#pragma unroll
  for (int cf = 0; cf < 4; ++cf) {
    int c0 = cgrp * 64 + cf * 16 + hi * 4;         // 4 consecutive channels
    float b0 = bv[c0], b1 = bv[c0 + 1], b2 = bv[c0 + 2], b3 = bv[c0 + 3];
#pragma unroll
    for (int pf = 0; pf < 4; ++pf) {
      int p = pgrp * 64 + pf * 16 + l15;
      f32x4 a = acc[cf][pf];
      unsigned int lo  = cvt_pk_bf16(fmaxf(a[0] + b0, 0.0f), fmaxf(a[1] + b1, 0.0f));
      unsigned int hi2 = cvt_pk_bf16(fmaxf(a[2] + b2, 0.0f), fmaxf(a[3] + b3, 0.0f));
      unsigned long long w = (unsigned long long)lo | ((unsigned long long)hi2 << 32);
      int byteoff = ((p * 256 + c0) * 2) ^ ((p & 7) << 4);
      *(unsigned long long*)((char*)dst + byteoff) = w;
    }
  }
}

// ---------------------------------------------------------------------------
// k1: one block = 128 points of one bbox row; 8 waves; 2 blocks/CU.
// ---------------------------------------------------------------------------
__global__ __launch_bounds__(THREADS, 4) void pn_main(
    const float* __restrict__ feat,
    const unsigned short* __restrict__ wp,
    const float* __restrict__ b1,
    const float* __restrict__ b2,
    const float* __restrict__ b3,
    const float* __restrict__ cW,
    float* __restrict__ out) {
  __shared__ unsigned short hA[128 * 256];   // 64 KB, swizzled bf16 h (in-place)
  __shared__ unsigned short hF[128 * 8];     // 2 KB: layer-1 B slice (k0..7)
  __shared__ float biasL[3 * 256];           // 3 KB
  __shared__ float whL[256];                 // 1 KB (cW[6..261])
  float* sPart = (float*)hF;                 // overlay: hF dead after L1 gemm

  const int tid  = threadIdx.x;
  const int lane = tid & 63;
  const int wave = tid >> 6;
  const int l15  = lane & 15;
  const int hi   = lane >> 4;
  const int cgrp = wave & 3;     // channel group (64 of 256)
  const int pgrp = wave >> 2;    // point group (64 of 128)

  const int blk = blockIdx.x;
  const int m   = blk >> 6;
  const int n0  = (blk & 63) << 7;
  const int g0  = m * 8192 + n0;

  // ---- stage biases + classifier hidden weights
  if (tid < 256) {
    biasL[tid]       = b1[tid];
    biasL[256 + tid] = b2[tid];
    biasL[512 + tid] = b3[tid];
    whL[tid]         = cW[6 + tid];
  }

  // ---- build hF (k0..7 slice, 2 zeros) + fdot in register
  float fdot = 0.0f;
  if (tid < 128) {
    const float* fp = feat + (g0 + tid) * 6;
    float f0 = fp[0], f1 = fp[1], f2 = fp[2], f3 = fp[3], f4 = fp[4], f5 = fp[5];
    fdot = f0 * cW[0] + f1 * cW[1] + f2 * cW[2] + f3 * cW[3] + f4 * cW[4] + f5 * cW[5];
    u32x4 v;
    v[0] = cvt_pk_bf16(f0, f1);
    v[1] = cvt_pk_bf16(f2, f3);
    v[2] = cvt_pk_bf16(f4, f5);
    v[3] = 0;
    *(u32x4*)(hF + tid * 8) = v;
  }
  __syncthreads();

  f32x4 acc[4][4];
  const f32x4 zz = {0.f, 0.f, 0.f, 0.f};
  const short8 zero8 = {0, 0, 0, 0, 0, 0, 0, 0};

  // ---- layer 1 (K padded to 32; only hi==0 k-slots are nonzero)
#pragma unroll
  for (int a = 0; a < 4; ++a)
#pragma unroll
    for (int b = 0; b < 4; ++b) acc[a][b] = zz;
  {
    short8 afr[4], bfr[4];
#pragma unroll
    for (int cf = 0; cf < 4; ++cf) {
      int ct = cgrp * 4 + cf;
      afr[cf] = *(const short8*)(wp + (((ct * 4 + hi) * 16 + l15) << 3));
    }
#pragma unroll
    for (int pf = 0; pf < 4; ++pf) {
      int p = pgrp * 64 + pf * 16 + l15;
      bfr[pf] = (hi == 0) ? *(const short8*)(hF + p * 8) : zero8;
    }
#pragma unroll
    for (int cf = 0; cf < 4; ++cf)
#pragma unroll
      for (int pf = 0; pf < 4; ++pf)
        acc[cf][pf] = __builtin_amdgcn_mfma_f32_16x16x32_bf16(
            afr[cf], bfr[pf], acc[cf][pf], 0, 0, 0);
  }
  epi_h(acc, hA, biasL + 0, cgrp, pgrp, l15, hi);
  __syncthreads();

  // ---- layer 2 (reads hA, writes hA in place after a barrier)
#pragma unroll
  for (int a = 0; a < 4; ++a)
#pragma unroll
    for (int b = 0; b < 4; ++b) acc[a][b] = zz;
  gemm256(wp + 8192, hA, cgrp, pgrp, l15, hi, acc);
  __syncthreads();                       // all h1 reads complete
  epi_h(acc, hA, biasL + 256, cgrp, pgrp, l15, hi);
  __syncthreads();                       // h2 visible

  // ---- layer 3 + classifier dot
#pragma unroll
  for (int a = 0; a < 4; ++a)
#pragma unroll
    for (int b = 0; b < 4; ++b) acc[a][b] = zz;
  gemm256(wp + 73728, hA, cgrp, pgrp, l15, hi, acc);

  float part[4] = {0.f, 0.f, 0.f, 0.f};
#pragma unroll
  for (int cf = 0; cf < 4; ++cf) {
    int c0 = cgrp * 64 + cf * 16 + hi * 4;
#pragma unroll
    for (int r = 0; r < 4; ++r) {
      int c = c0 + r;
      float bb = biasL[512 + c];
      float wv = whL[c];
#pragma unroll
      for (int pf = 0; pf < 4; ++pf)
        part[pf] += fmaxf(acc[cf][pf][r] + bb, 0.0f) * wv;
    }
  }
  // reduce across hi groups (same point, different channels)
#pragma unroll
  for (int off = 16; off < 64; off <<= 1)
#pragma unroll
    for (int pf = 0; pf < 4; ++pf)
      part[pf] += __shfl_xor(part[pf], off);
  if (hi == 0) {
#pragma unroll
    for (int pf = 0; pf < 4; ++pf)
      sPart[cgrp * 128 + pgrp * 64 + pf * 16 + l15] = part[pf];
  }
  __syncthreads();

  if (tid < 128) {
    float s = sPart[tid] + sPart[128 + tid] + sPart[256 + tid] + sPart[384 + tid]
            + fdot;
    out[g0 + tid] = s;   // raw s1; rescaled by pn_finalize
  }
}

// ---------------------------------------------------------------------------
// k2: per-bbox min/max rescale to [-1,1], in place.
// ---------------------------------------------------------------------------
__global__ void pn_finalize(float* __restrict__ out) {
  __shared__ float smn[4], smx[4];
  int mrow = blockIdx.x;
  float* row = out + mrow * 8192;
  float v[32];
  float mn = 1e30f, mx = -1e30f;
#pragma unroll
  for (int i = 0; i < 32; ++i) {
    v[i] = row[threadIdx.x + i * 256];
    mn = fminf(mn, v[i]);
    mx = fmaxf(mx, v[i]);
  }
#pragma unroll
  for (int off = 1; off < 64; off <<= 1) {
    mn = fminf(mn, __shfl_xor(mn, off));
    mx = fmaxf(mx, __shfl_xor(mx, off));
  }
  int w = threadIdx.x >> 6;
  if ((threadIdx.x & 63) == 0) { smn[w] = mn; smx[w] = mx; }
  __syncthreads();
  mn = fminf(fminf(smn[0], smn[1]), fminf(smn[2], smn[3]));
  mx = fmaxf(fmaxf(smx[0], smx[1]), fmaxf(smx[2], smx[3]));
  float sc = 2.0f / (mx - mn);
#pragma unroll
  for (int i = 0; i < 32; ++i)
    row[threadIdx.x + i * 256] = (v[i] - mn) * sc - 1.0f;
}

// ---------------------------------------------------------------------------
extern "C" void kernel_launch(void* const* d_in, const int* in_sizes, int n_in,
                              void* d_out, int out_size, void* d_ws, size_t ws_size,
                              hipStream_t stream) {
  const float* feat = (const float*)d_in[0];
  const float* eW1  = (const float*)d_in[1];
  const float* eb1  = (const float*)d_in[2];
  const float* eW2  = (const float*)d_in[3];
  const float* eb2  = (const float*)d_in[4];
  const float* eW3  = (const float*)d_in[5];
  const float* eb3  = (const float*)d_in[6];
  // sW*/sb* (7..12) and cb (14) cancel in the per-row rescale -- unused.
  const float* cW   = (const float*)d_in[13];
  float* out = (float*)d_out;
  unsigned short* wpack = (unsigned short*)d_ws;   // 278,528 B of ws

  pn_pack<<<544, 256, 0, stream>>>(eW1, eW2, eW3, wpack);
  pn_main<<<4096, THREADS, 0, stream>>>(feat, wpack, eb1, eb2, eb3, cW, out);
  pn_finalize<<<64, 256, 0, stream>>>(out);
}

// Round 3
// 145.096 us; speedup vs baseline: 2.1572x; 2.1572x over previous
//
#include <hip/hip_runtime.h>

// PointNet fused kernel for MI355X (gfx950) — round 3.
//
// Algebra: segment-MLP + cb are per-row constants -> cancel in the per-row
// min/max rescale. Only s1[m,n] = feat·cW[0:6] + relu(MLP3(feat))·cW[6:262]
// matters, then per-row rescale to [-1,1].
//
// Round-3 change vs round 2: __launch_bounds__(512,4) capped VGPR at 128 and
// caused massive scratch spilling (FETCH 325 MB, WRITE 649 MB per dispatch).
// Revert to (512,1): natural allocation ~104 VGPR fits 4 waves/SIMD anyway;
// occupancy is LDS-limited at 2 blocks/CU (70 KB each), which we keep.

typedef __attribute__((ext_vector_type(8))) short short8;   // 8 bf16
typedef __attribute__((ext_vector_type(4))) float f32x4;    // MFMA accum
typedef __attribute__((ext_vector_type(4))) unsigned int u32x4;

#define THREADS 512

__device__ __forceinline__ unsigned short f2bf(float f) {
  union { float f; unsigned int u; } x; x.f = f;
  unsigned int r = x.u + 0x7fffu + ((x.u >> 16) & 1u);   // RNE
  return (unsigned short)(r >> 16);
}

__device__ __forceinline__ unsigned int cvt_pk_bf16(float lo, float hi) {
  unsigned int r;
  asm("v_cvt_pk_bf16_f32 %0, %1, %2" : "=v"(r) : "v"(lo), "v"(hi));
  return r;
}

// ---------------------------------------------------------------------------
// k0: pack weights into MFMA A-fragment order:
//   idx(s,ct,hi,col,j) = (((s*16+ct)*4+hi)*16+col)*8 + j
//   k = s*32 + hi*8 + j (zero past Kreal), c = ct*16 + col
// Regions (ushort): W1 @0 (8192), W2 @8192 (65536), W3 @73728 (65536)
// ---------------------------------------------------------------------------
__global__ void pn_pack(const float* __restrict__ W1,
                        const float* __restrict__ W2,
                        const float* __restrict__ W3,
                        unsigned short* __restrict__ wp) {
  int e = blockIdx.x * 256 + threadIdx.x;           // 0 .. 139263
  const float* src; int Kreal, base, r;
  if (e < 8192)       { src = W1; Kreal = 6;   base = 0;     r = e; }
  else if (e < 73728) { src = W2; Kreal = 256; base = 8192;  r = e - 8192; }
  else                { src = W3; Kreal = 256; base = 73728; r = e - 73728; }
  int j   = r & 7;
  int col = (r >> 3) & 15;
  int hi  = (r >> 7) & 3;
  int ct  = (r >> 9) & 15;
  int s   = r >> 13;
  int k = s * 32 + hi * 8 + j;
  int c = ct * 16 + col;
  float v = (k < Kreal) ? src[k * 256 + c] : 0.0f;
  wp[base + r] = f2bf(v);
}

// ---------------------------------------------------------------------------
// k1 helpers
// ---------------------------------------------------------------------------
__device__ __forceinline__ void gemm256(const unsigned short* __restrict__ wpL,
                                        const unsigned short* hbuf,
                                        int cgrp, int pgrp, int l15, int hi,
                                        f32x4 (&acc)[4][4]) {
#pragma unroll
  for (int ks = 0; ks < 8; ++ks) {
    short8 afr[4], bfr[4];
#pragma unroll
    for (int cf = 0; cf < 4; ++cf) {               // A = W fragments (global)
      int ct = cgrp * 4 + cf;
      afr[cf] = *(const short8*)(wpL + (((((ks * 16 + ct) * 4) + hi) * 16 + l15) << 3));
    }
#pragma unroll
    for (int pf = 0; pf < 4; ++pf) {               // B = h fragments (LDS, swz)
      int p = pgrp * 64 + pf * 16 + l15;
      int byteoff = ((p * 256 + ks * 32 + hi * 8) * 2) ^ ((p & 7) << 4);
      bfr[pf] = *(const short8*)((const char*)hbuf + byteoff);
    }
#pragma unroll
    for (int cf = 0; cf < 4; ++cf)
#pragma unroll
      for (int pf = 0; pf < 4; ++pf)
        acc[cf][pf] = __builtin_amdgcn_mfma_f32_16x16x32_bf16(
            afr[cf], bfr[pf], acc[cf][pf], 0, 0, 0);
  }
}

// bias + relu -> bf16 (cvt_pk) -> swizzled h buffer, b64 writes
__device__ __forceinline__ void epi_h(f32x4 (&acc)[4][4], unsigned short* dst,
                                      const float* bv,
                                      int cgrp, int pgrp, int l15, int hi) {
#pragma unroll
  for (int cf = 0; cf < 4; ++cf) {
    int c0 = cgrp * 64 + cf * 16 + hi * 4;         // 4 consecutive channels
    float b0 = bv[c0], b1 = bv[c0 + 1], b2 = bv[c0 + 2], b3 = bv[c0 + 3];
#pragma unroll
    for (int pf = 0; pf < 4; ++pf) {
      int p = pgrp * 64 + pf * 16 + l15;
      f32x4 a = acc[cf][pf];
      unsigned int lo  = cvt_pk_bf16(fmaxf(a[0] + b0, 0.0f), fmaxf(a[1] + b1, 0.0f));
      unsigned int hi2 = cvt_pk_bf16(fmaxf(a[2] + b2, 0.0f), fmaxf(a[3] + b3, 0.0f));
      unsigned long long w = (unsigned long long)lo | ((unsigned long long)hi2 << 32);
      int byteoff = ((p * 256 + c0) * 2) ^ ((p & 7) << 4);
      *(unsigned long long*)((char*)dst + byteoff) = w;
    }
  }
}

// ---------------------------------------------------------------------------
// k1: one block = 128 points of one bbox row; 8 waves; 2 blocks/CU.
// ---------------------------------------------------------------------------
__global__ __launch_bounds__(THREADS, 1) void pn_main(
    const float* __restrict__ feat,
    const unsigned short* __restrict__ wp,
    const float* __restrict__ b1,
    const float* __restrict__ b2,
    const float* __restrict__ b3,
    const float* __restrict__ cW,
    float* __restrict__ out) {
  __shared__ unsigned short hA[128 * 256];   // 64 KB, swizzled bf16 h (in-place)
  __shared__ unsigned short hF[128 * 8];     // 2 KB: layer-1 B slice (k0..7)
  __shared__ float biasL[3 * 256];           // 3 KB
  __shared__ float whL[256];                 // 1 KB (cW[6..261])
  float* sPart = (float*)hF;                 // overlay: hF dead after L1 gemm

  const int tid  = threadIdx.x;
  const int lane = tid & 63;
  const int wave = tid >> 6;
  const int l15  = lane & 15;
  const int hi   = lane >> 4;
  const int cgrp = wave & 3;     // channel group (64 of 256)
  const int pgrp = wave >> 2;    // point group (64 of 128)

  const int blk = blockIdx.x;
  const int m   = blk >> 6;
  const int n0  = (blk & 63) << 7;
  const int g0  = m * 8192 + n0;

  // ---- stage biases + classifier hidden weights
  if (tid < 256) {
    biasL[tid]       = b1[tid];
    biasL[256 + tid] = b2[tid];
    biasL[512 + tid] = b3[tid];
    whL[tid]         = cW[6 + tid];
  }

  // ---- build hF (k0..7 slice, 2 zeros) + fdot in register
  float fdot = 0.0f;
  if (tid < 128) {
    const float* fp = feat + (g0 + tid) * 6;
    float f0 = fp[0], f1 = fp[1], f2 = fp[2], f3 = fp[3], f4 = fp[4], f5 = fp[5];
    fdot = f0 * cW[0] + f1 * cW[1] + f2 * cW[2] + f3 * cW[3] + f4 * cW[4] + f5 * cW[5];
    u32x4 v;
    v[0] = cvt_pk_bf16(f0, f1);
    v[1] = cvt_pk_bf16(f2, f3);
    v[2] = cvt_pk_bf16(f4, f5);
    v[3] = 0;
    *(u32x4*)(hF + tid * 8) = v;
  }
  __syncthreads();

  f32x4 acc[4][4];
  const f32x4 zz = {0.f, 0.f, 0.f, 0.f};
  const short8 zero8 = {0, 0, 0, 0, 0, 0, 0, 0};

  // ---- layer 1 (K padded to 32; only hi==0 k-slots are nonzero)
#pragma unroll
  for (int a = 0; a < 4; ++a)
#pragma unroll
    for (int b = 0; b < 4; ++b) acc[a][b] = zz;
  {
    short8 afr[4], bfr[4];
#pragma unroll
    for (int cf = 0; cf < 4; ++cf) {
      int ct = cgrp * 4 + cf;
      afr[cf] = *(const short8*)(wp + (((ct * 4 + hi) * 16 + l15) << 3));
    }
#pragma unroll
    for (int pf = 0; pf < 4; ++pf) {
      int p = pgrp * 64 + pf * 16 + l15;
      bfr[pf] = (hi == 0) ? *(const short8*)(hF + p * 8) : zero8;
    }
#pragma unroll
    for (int cf = 0; cf < 4; ++cf)
#pragma unroll
      for (int pf = 0; pf < 4; ++pf)
        acc[cf][pf] = __builtin_amdgcn_mfma_f32_16x16x32_bf16(
            afr[cf], bfr[pf], acc[cf][pf], 0, 0, 0);
  }
  epi_h(acc, hA, biasL + 0, cgrp, pgrp, l15, hi);
  __syncthreads();

  // ---- layer 2 (reads hA, writes hA in place after a barrier)
#pragma unroll
  for (int a = 0; a < 4; ++a)
#pragma unroll
    for (int b = 0; b < 4; ++b) acc[a][b] = zz;
  gemm256(wp + 8192, hA, cgrp, pgrp, l15, hi, acc);
  __syncthreads();                       // all h1 reads complete
  epi_h(acc, hA, biasL + 256, cgrp, pgrp, l15, hi);
  __syncthreads();                       // h2 visible

  // ---- layer 3 + classifier dot
#pragma unroll
  for (int a = 0; a < 4; ++a)
#pragma unroll
    for (int b = 0; b < 4; ++b) acc[a][b] = zz;
  gemm256(wp + 73728, hA, cgrp, pgrp, l15, hi, acc);

  float part[4] = {0.f, 0.f, 0.f, 0.f};
#pragma unroll
  for (int cf = 0; cf < 4; ++cf) {
    int c0 = cgrp * 64 + cf * 16 + hi * 4;
#pragma unroll
    for (int r = 0; r < 4; ++r) {
      int c = c0 + r;
      float bb = biasL[512 + c];
      float wv = whL[c];
#pragma unroll
      for (int pf = 0; pf < 4; ++pf)
        part[pf] += fmaxf(acc[cf][pf][r] + bb, 0.0f) * wv;
    }
  }
  // reduce across hi groups (same point, different channels)
#pragma unroll
  for (int off = 16; off < 64; off <<= 1)
#pragma unroll
    for (int pf = 0; pf < 4; ++pf)
      part[pf] += __shfl_xor(part[pf], off);
  if (hi == 0) {
#pragma unroll
    for (int pf = 0; pf < 4; ++pf)
      sPart[cgrp * 128 + pgrp * 64 + pf * 16 + l15] = part[pf];
  }
  __syncthreads();

  if (tid < 128) {
    float s = sPart[tid] + sPart[128 + tid] + sPart[256 + tid] + sPart[384 + tid]
            + fdot;
    out[g0 + tid] = s;   // raw s1; rescaled by pn_finalize
  }
}

// ---------------------------------------------------------------------------
// k2: per-bbox min/max rescale to [-1,1], in place.
// ---------------------------------------------------------------------------
__global__ void pn_finalize(float* __restrict__ out) {
  __shared__ float smn[4], smx[4];
  int mrow = blockIdx.x;
  float* row = out + mrow * 8192;
  float v[32];
  float mn = 1e30f, mx = -1e30f;
#pragma unroll
  for (int i = 0; i < 32; ++i) {
    v[i] = row[threadIdx.x + i * 256];
    mn = fminf(mn, v[i]);
    mx = fmaxf(mx, v[i]);
  }
#pragma unroll
  for (int off = 1; off < 64; off <<= 1) {
    mn = fminf(mn, __shfl_xor(mn, off));
    mx = fmaxf(mx, __shfl_xor(mx, off));
  }
  int w = threadIdx.x >> 6;
  if ((threadIdx.x & 63) == 0) { smn[w] = mn; smx[w] = mx; }
  __syncthreads();
  mn = fminf(fminf(smn[0], smn[1]), fminf(smn[2], smn[3]));
  mx = fmaxf(fmaxf(smx[0], smx[1]), fmaxf(smx[2], smx[3]));
  float sc = 2.0f / (mx - mn);
#pragma unroll
  for (int i = 0; i < 32; ++i)
    row[threadIdx.x + i * 256] = (v[i] - mn) * sc - 1.0f;
}

// ---------------------------------------------------------------------------
extern "C" void kernel_launch(void* const* d_in, const int* in_sizes, int n_in,
                              void* d_out, int out_size, void* d_ws, size_t ws_size,
                              hipStream_t stream) {
  const float* feat = (const float*)d_in[0];
  const float* eW1  = (const float*)d_in[1];
  const float* eb1  = (const float*)d_in[2];
  const float* eW2  = (const float*)d_in[3];
  const float* eb2  = (const float*)d_in[4];
  const float* eW3  = (const float*)d_in[5];
  const float* eb3  = (const float*)d_in[6];
  // sW*/sb* (7..12) and cb (14) cancel in the per-row rescale -- unused.
  const float* cW   = (const float*)d_in[13];
  float* out = (float*)d_out;
  unsigned short* wpack = (unsigned short*)d_ws;   // 278,528 B of ws

  pn_pack<<<544, 256, 0, stream>>>(eW1, eW2, eW3, wpack);
  pn_main<<<4096, THREADS, 0, stream>>>(feat, wpack, eb1, eb2, eb3, cW, out);
  pn_finalize<<<64, 256, 0, stream>>>(out);
}